// Round 16
// baseline (120.944 us; speedup 1.0000x reference)
//
#include <hip/hip_runtime.h>
#include <stdint.h>

typedef unsigned long long ull;
typedef float f4v __attribute__((ext_vector_type(4)));

#define NUM_CLASSES 21
#define NFG 20
#define TOPK 200
#define KPRE 256
#define NTHR 512                 // nms block size (8 waves)
#define CONF_TH 0.01f
#define NMS_TH 0.45f
#define VAR0 0.1f
#define VAR1 0.2f
#define NV9 9                    // ceil((8732/2)/512) uint regs (2 u16 scores each)
#define T16_LO 0x3C23u           // __float_as_uint(0.01f)>>16 (~0.00995 floor)
#define T16_HI 0x3F81u           // just above 1.0f in top-16 bits
// skewed LDS slot: g, g+64, g+128, g+192 land in different banks
#define BSLOT(g) ((g) + ((g) >> 6))

// Kernel 1: unchanged from R14/R15 (verified). Per-row softmax normalizers
// (mx,s) + truncated u16 scores, transposed [B][NFG][P] (13.4 MB).
__global__ __launch_bounds__(256) void rownorm16_kernel(
    const float* __restrict__ conf, float2* __restrict__ norm,
    ushort* __restrict__ probs16, int B, int P) {
    __shared__ __align__(16) float buf[256 * NUM_CLASSES];   // 21504 B
    __shared__ __align__(16) ushort b16[NFG * 256];          // 10240 B transpose
    const int t = threadIdx.x;
    const int nch = (P + 255) >> 8;              // 35

    const int id = blockIdx.x;
    int b, chk;
    if ((B & 7) == 0) {
        int r = id & 7, m = id >> 3;
        int q = m / nch;
        b = r + (q << 3);
        chk = m - q * nch;
    } else {
        b = id / nch;
        chk = id - b * nch;
    }
    const int p0 = chk << 8;
    const int cnt = min(256, P - p0);
    const float* src = conf + ((size_t)b * P + p0) * NUM_CLASSES;  // 16B aligned

    if (cnt == 256) {
        const f4v* s4 = (const f4v*)src;
        f4v* b4 = (f4v*)buf;
#pragma unroll
        for (int k = 0; k < 6; ++k) {
            int i = (k << 8) + t;
            if (i < (256 * NUM_CLASSES) / 4) b4[i] = s4[i];
        }
    } else {
        int n = cnt * NUM_CLASSES;
        for (int i = t; i < n; i += 256) buf[i] = src[i];
    }
    __syncthreads();

    if (t < cnt) {
        const float* row = buf + t * NUM_CLASSES;   // stride 21 => 2-way (free)
        float x[NUM_CLASSES];
        float mx = row[0];
        x[0] = mx;
#pragma unroll
        for (int j = 1; j < NUM_CLASSES; ++j) { x[j] = row[j]; mx = fmaxf(mx, x[j]); }
        float s = 0.f;
#pragma unroll
        for (int j = 0; j < NUM_CLASSES; ++j) { x[j] = expf(x[j] - mx); s += x[j]; }
        ull nv = (ull)__float_as_uint(mx) | ((ull)__float_as_uint(s) << 32);
        __hip_atomic_store((ull*)(norm + (size_t)b * P + p0 + t), nv,
                           __ATOMIC_RELAXED, __HIP_MEMORY_SCOPE_AGENT);
#pragma unroll
        for (int c = 1; c < NUM_CLASSES; ++c) {
            float v = x[c] / s;                     // true IEEE div (exact score)
            b16[(c - 1) * 256 + t] = (ushort)(__float_as_uint(v) >> 16);
        }
    }
    __syncthreads();

    if (cnt == 256) {
        const uint* s32 = (const uint*)b16;
#pragma unroll
        for (int k = 0; k < 10; ++k) {
            int e = (k << 8) + t;
            int c = e >> 7;
            int q = e & 127;
            uint* dstu = (uint*)(probs16 + ((size_t)b * NFG + c) * P + p0);
            __hip_atomic_store(dstu + q, s32[(c << 7) + q],
                               __ATOMIC_RELAXED, __HIP_MEMORY_SCOPE_AGENT);
        }
    } else {
        for (int e = t; e < NFG * cnt; e += 256) {
            int c = e / cnt;
            int f = e - c * cnt;
            __hip_atomic_store(probs16 + ((size_t)b * NFG + c) * P + p0 + f,
                               b16[c * 256 + f],
                               __ATOMIC_RELAXED, __HIP_MEMORY_SCOPE_AGENT);
        }
    }
}

// Kernel 2: one block per (b, fg_class), 512 threads. R15 post-mortem: nms is
// serial-latency/barrier bound (VALU cuts -60% moved it only -1.2us). This
// round: SINGLE-WAVE F2 — wave 0 resolves all 4 suppression tiles back-to-back
// with zero barriers (tile k consumes smask + kept_mask[<k], all wave-0
// local), publishes kept_mask[4], ONE barrier releases the block. Replaces 4
// sequential barrier phases (+straggle). Suppression semantics bit-identical.
__global__ __launch_bounds__(NTHR) void nms_topk_kernel(
    const float* __restrict__ conf, const float2* __restrict__ norm,
    const ushort* __restrict__ probs16, const float* __restrict__ loc,
    const float* __restrict__ prior, float* __restrict__ out, int B, int P) {

    __shared__ ull arr[2 * KPRE];               // 512 sort keys
    __shared__ ull arr2[2 * KPRE];              // double buffer for sort LDS stages
    __shared__ int wsum[2][8];
    __shared__ int s_cnt;
    __shared__ float4 sbox[KPRE + (KPRE >> 6)]; // skewed (BSLOT)
    __shared__ float sarea[KPRE + (KPRE >> 6)];
    __shared__ ull smask[KPRE][5];              // padded stride 40B: 2-way (free)
    __shared__ ull kept_mask[4];

    const int t = threadIdx.x;
    const int lane = t & 63;
    const int wid = t >> 6;                     // 0..7
    const ull lmask_lt = (1ULL << lane) - 1ULL;

    const int g = blockIdx.x;
    int b, c;
    if ((B & 7) == 0) {
        int k = g >> 3;
        b = ((k / NFG) << 3) + (g & 7);
        c = k - (k / NFG) * NFG;
    } else {
        b = g / NFG;
        c = g - (g / NFG) * NFG;
    }
    const int pair = b * NFG + c;
    const int nq = P >> 1;                      // 4366 uints (P even)

    // A: u16 scores, pre-split into lo/hi halves.
    unsigned int lo16[NV9], hi16[NV9];
    {
        const uint* sp16 = (const uint*)(probs16 + (size_t)pair * P);
#pragma unroll
        for (int i = 0; i < NV9; ++i) {
            int q = (i << 9) + t;
            unsigned int u = (q < nq) ? sp16[q] : 0u;   // 0 => never >= T16
            lo16[i] = u & 0xFFFFu;
            hi16[i] = u >> 16;
        }
    }
    // score reg (i,h) corresponds to prior p = (((i<<9)+t)<<1)+h

    // B: WAVE-LOCAL coarse binary search on u16 (10 iters, no barriers).
    // Per-wave target = KPRE/8 = 32; global T16 = min of 8 wave thresholds.
    {
        unsigned int lo = T16_LO, hi = T16_HI;
        while (hi - lo > 1u) {
            unsigned int mid = lo + ((hi - lo) >> 1);
            int cc = 0;
#pragma unroll
            for (int i = 0; i < NV9; ++i) {
                cc += __popcll(__ballot(lo16[i] >= mid));
                cc += __popcll(__ballot(hi16[i] >= mid));
            }
            if (cc >= KPRE / 8) lo = mid; else hi = mid;
        }
        if (lane == 0) wsum[0][wid] = (int)lo;
    }
    __syncthreads();
    unsigned int T16;
    {
        int m = wsum[0][0];
#pragma unroll
        for (int w = 1; w < 8; ++w) m = min(m, wsum[0][w]);
        T16 = (unsigned int)m;
    }

    // C: ballot-compaction of candidate indices (cap 512) + exact fallback.
    int nval;
    for (int attempt = 0;; ++attempt) {
        if (t == 0) s_cnt = 0;
        __syncthreads();
        int wtot = 0;
#pragma unroll
        for (int i = 0; i < NV9; ++i) {
            wtot += __popcll(__ballot(lo16[i] >= T16));
            wtot += __popcll(__ballot(hi16[i] >= T16));
        }
        int wbase = 0;
        if (lane == 0) wbase = atomicAdd(&s_cnt, wtot);
        wbase = __shfl(wbase, 0);
        int run = wbase;
#pragma unroll
        for (int i = 0; i < NV9; ++i) {
#pragma unroll
            for (int h = 0; h < 2; ++h) {
                unsigned int bits16 = h ? hi16[i] : lo16[i];
                bool pred = (bits16 >= T16);
                ull bal = __ballot(pred);
                if (pred) {
                    int slot = run + __popcll(bal & lmask_lt);
                    if (slot < 2 * KPRE)
                        arr[slot] = (ull)(unsigned int)((((i << 9) + t) << 1) + h);
                }
                run += __popcll(bal);
            }
        }
        __syncthreads();
        if (s_cnt <= 2 * KPRE || attempt == 1) { nval = min(s_cnt, 2 * KPRE); break; }
        unsigned int lo = T16, hi = T16_HI;
        int it = 0;
        while (hi - lo > 1u) {
            unsigned int mid = lo + ((hi - lo) >> 1);
            int cc = 0;
#pragma unroll
            for (int i = 0; i < NV9; ++i) {
                cc += __popcll(__ballot(lo16[i] >= mid));
                cc += __popcll(__ballot(hi16[i] >= mid));
            }
            if (lane == 0) wsum[it & 1][wid] = cc;
            __syncthreads();
            int totc = 0;
#pragma unroll
            for (int w = 0; w < 8; ++w) totc += wsum[it & 1][w];
            if (totc >= KPRE) lo = mid; else hi = mid;
            ++it;
        }
        T16 = lo;
    }

    if (t >= nval) arr[t] = (ull)0xFFFFFFFFu;   // sentinel index (invalid)
    __syncthreads();

    // C2: gather exact fp32 score for MY candidate slot (1/thread).
    // UNSIGNED bounds guard (R11 lesson: sentinel -1 must be invalid).
    const float* cb = conf + (size_t)b * P * NUM_CLASSES + (c + 1);
    const float2* nb = norm + (size_t)b * P;
    ull k0;
    {
        unsigned int pa = (unsigned int)arr[t];
        if (pa < (unsigned int)P) {
            float xa = cb[(size_t)pa * NUM_CLASSES];
            float2 ma = nb[pa];
            float v = expf(xa - ma.x) / ma.y;
            k0 = ((ull)__float_as_uint(v) << 32) | (unsigned int)(~pa);
        } else {
            k0 = 0ULL;
        }
    }
    __syncthreads();

    // D: 512-wide bitonic sort, ONE key/thread, descending.
    // key = (bits<<32)|~idx => value desc, index asc (JAX tie-break).
    {
        int lstage = 0;
#pragma unroll
        for (int kk = 2; kk <= 2 * KPRE; kk <<= 1) {
#pragma unroll
            for (int j = kk >> 1; j > 0; j >>= 1) {
                bool amLow = ((t & j) == 0);
                bool d0 = ((t & kk) == 0);
                if (j >= 64) {
                    ull* A = (lstage & 1) ? arr : arr2;
                    ++lstage;
                    A[t] = k0;
                    __syncthreads();
                    ull o0 = A[t ^ j];
                    k0 = (d0 == amLow) ? ((k0 > o0) ? k0 : o0) : ((k0 > o0) ? o0 : k0);
                } else {
                    ull o0 = __shfl_xor(k0, j);
                    k0 = (d0 == amLow) ? ((k0 > o0) ? k0 : o0) : ((k0 > o0) ? o0 : k0);
                }
            }
        }
    }
    const ull key = k0;    // threads 0..255 hold the top-256, sorted descending

    // E: decode candidate t (threads < 256 only)
    float v = 0.f, x1 = 0.f, y1 = 0.f, x2 = 0.f, y2 = 0.f;
    if (t < KPRE) {
        v = __uint_as_float((unsigned int)(key >> 32));
        int idx = (int)(~(unsigned int)(key & 0xFFFFFFFFu));
        if (idx < 0 || idx >= P) { idx = 0; v = 0.f; }

        const float4 lv = *(const float4*)(loc + ((size_t)b * P + idx) * 4);
        const float4 pv = *(const float4*)(prior + (size_t)idx * 4);
        float cx = pv.x + (lv.x * VAR0) * pv.z;
        float cy = pv.y + (lv.y * VAR0) * pv.w;
        float w = pv.z * expf(lv.z * VAR1);
        float h = pv.w * expf(lv.w * VAR1);
        x1 = cx - w * 0.5f;
        y1 = cy - h * 0.5f;
        x2 = x1 + w;
        y2 = y1 + h;
        float myarea = fmaxf(x2 - x1, 0.f) * fmaxf(y2 - y1, 0.f);
        sbox[BSLOT(t)] = make_float4(x1, y1, x2, y2);
        sarea[BSLOT(t)] = myarea;
    }
    // publish per-candidate validity for F2's wave-0 resolve
    if (t < 4 && lane < 4) { }      // (no-op; kept_mask written by wave 0 below)
    __syncthreads();

    // F1: wave-per-w2-strip mask build (verified R15). Exact div-free IoU:
    // RN(inter/u) > 0.45f <=> inter > M*u, M = midpoint(0.45f, succ(0.45f)).
    {
        const double Mth = 30198989.0 / 67108864.0;
#pragma unroll
        for (int w2 = 0; w2 < 4; ++w2) {
            int gg = (w2 << 6) + lane;
            float4 gb = sbox[BSLOT(gg)];
            float ga = sarea[BSLOT(gg)];
            for (int r = (w2 << 6) + wid; r < KPRE; r += 8) {
                float4 rb = sbox[BSLOT(r)];     // wave-uniform -> broadcast
                float ra = sarea[BSLOT(r)];
                float lx = fmaxf(gb.x, rb.x), ly = fmaxf(gb.y, rb.y);
                float rx = fminf(gb.z, rb.z), ry = fminf(gb.w, rb.w);
                float iw = fmaxf(rx - lx, 0.f), ih = fmaxf(ry - ly, 0.f);
                float inter = iw * ih;
                float uni = fmaxf(ga + ra - inter, 1e-9f);
                bool s = ((double)inter > Mth * (double)uni);
                ull bal = __ballot(s);
                if (lane == 0) smask[r][w2] = bal;
            }
        }
        // each wave also publishes validity (v > CONF_TH) of its E-candidates?
        // validity is only defined for t<256; capture it via ballot per wave:
        if (wid < 4) {
            ull vb = __ballot(t < KPRE && v > CONF_TH);
            if (lane == 0) smask[(wid << 6)][4] = vb;   // stash in pad column
        }
    }
    __syncthreads();

    // F2: SINGLE-WAVE resolve. Wave 0 processes tiles 0..3 back-to-back with
    // no barriers (tile k needs smask rows 64k..64k+63 and kept_mask[<k],
    // all wave-0 local), then publishes kept_mask[4]; one barrier releases.
    // Identical suppression semantics to the 4-phase version.
    if (wid == 0) {
        ull keptm[4];
#pragma unroll
        for (int w2 = 0; w2 < 4; ++w2) {
            int r = (w2 << 6) + lane;           // my row in this tile
            ull mrow[4];
            mrow[0] = smask[r][0];
            mrow[1] = (w2 >= 1) ? smask[r][1] : 0ULL;
            mrow[2] = (w2 >= 2) ? smask[r][2] : 0ULL;
            mrow[3] = (w2 >= 3) ? smask[r][3] : 0ULL;
            mrow[w2] &= lmask_lt;               // diagonal: only earlier cols
            int al = (int)((smask[(w2 << 6)][4] >> lane) & 1ULL);  // validity
            if (w2 > 0 && (mrow[0] & keptm[0])) al = 0;
            if (w2 > 1 && (mrow[1] & keptm[1])) al = 0;
            if (w2 > 2 && (mrow[2] & keptm[2])) al = 0;
            ull mw = mrow[w2];
            ull validb = __ballot(al != 0);
            ull todo = __ballot((mw & validb) != 0ULL) & validb;
            ull kept = validb & ~todo;
            while (todo) {
                int i = __builtin_ctzll(todo);
                ull row = __shfl(mw, i);
                if ((row & kept) == 0ULL) kept |= (1ULL << i);
                todo &= (todo - 1ULL);
            }
            keptm[w2] = kept;
        }
        if (lane < 4) kept_mask[lane] = keptm[lane];
    }
    __syncthreads();

    // G: derive alive/rank from published kept_mask (t < 256 relevant)
    int alive = 0, rank = 0, total = 0;
    if (t < KPRE) {
        ull mykept = kept_mask[wid];
        alive = (int)((mykept >> lane) & 1ULL);
#pragma unroll
        for (int w2 = 0; w2 < 4; ++w2)
            if (w2 < wid) rank += __popcll(kept_mask[w2]);
        rank += __popcll(mykept & lmask_lt);
    }
#pragma unroll
    for (int w2 = 0; w2 < 4; ++w2) total += __popcll(kept_mask[w2]);

    float* orow = out + (size_t)pair * TOPK * 5;
    if (alive && rank < TOPK) {
        float* o = orow + rank * 5;
        o[0] = v; o[1] = x1; o[2] = y1; o[3] = x2; o[4] = y2;
    }
    if (t < TOPK && t >= total) {
        float* o = orow + t * 5;
        o[0] = 0.f; o[1] = 0.f; o[2] = 0.f; o[3] = 0.f; o[4] = 0.f;
    }
}

extern "C" void kernel_launch(void* const* d_in, const int* in_sizes, int n_in,
                              void* d_out, int out_size, void* d_ws, size_t ws_size,
                              hipStream_t stream) {
    const float* loc = (const float*)d_in[0];
    const float* conf = (const float*)d_in[1];
    const float* prior = (const float*)d_in[2];
    float* out = (float*)d_out;

    int P = in_sizes[2] / 4;                // 8732
    int B = in_sizes[0] / (4 * P);          // 32
    int nch = (P + 255) / 256;              // 35

    float2* norm = (float2*)d_ws;                                   // 2.23 MB
    ushort* probs16 = (ushort*)((char*)d_ws + (size_t)B * P * 8);   // 11.17 MB (16B-aligned)

    rownorm16_kernel<<<dim3(B * nch), 256, 0, stream>>>(conf, norm, probs16, B, P);
    nms_topk_kernel<<<B * NFG, NTHR, 0, stream>>>(conf, norm, probs16, loc, prior, out, B, P);
}